// Round 5
// baseline (78.467 us; speedup 1.0000x reference)
//
#include <hip/hip_runtime.h>
#include <math.h>

#define BB 8
#define TT 2048
#define VV 10
#define HH 5
#define CAP 64            // candidate-table capacity per head (expected ~14)
#define THR 0.011         // residue window; winner provably within 7.63e-3

// Single fused kernel. One block = 64 (b,t) rows, 320 threads (5 waves).
//
// score(b,h,t,s) = K * x0[b,s] * cos((s-t)+off_h) - 1e4*[s>t],
//   K = qk^2/sqrt(2) * x0[b,t]  (~4.6e10 scale), x0 in [999.9798, 1000].
// Softmax over these is one-hot => att_h = d[argmax]. The winner's residue
// r = (o+off_h) mod 2pi obeys |r| <= 7.63e-3 < THR (max circle gap 8.3e-3
// + x0 spread 0.0202 + mask 2.2e-4, all normalized by x0min). So per head
// the candidate offsets o=s-t form a fixed ~14-entry subset of [-2047,2047],
// independent of t and b.
//
// Phase 0: every block rebuilds the 5 tables in LDS (4095 offsets x 5 heads
//          / 320 threads ~= 65 cheap f64 checks per thread; ~70 hits).
// Phase 1: wave w scores head w for 64 consecutive rows (uniform loop count,
//          no divergence); f64 math identical to the R2/R3/R4-validated form.
// Phase 2: wave 0 runs the f32 epilogue (attention update + MLP + decode).
__global__ __launch_bounds__(320) void transformer_fused(
    const int* __restrict__ ids,
    const float* __restrict__ o_w,
    const float* __restrict__ w1_abc,
    const float* __restrict__ w2_s,
    const float* __restrict__ embed_const,
    const float* __restrict__ decode_eps,
    const float* __restrict__ qk_scale,
    const float* __restrict__ rope_offsets,
    float* __restrict__ out)
{
    __shared__ float bdL[64][HH + 1];
    __shared__ int oL[HH][CAP];
    __shared__ double crL[HH][CAP];
    __shared__ int cntL[HH];

    const int tid = threadIdx.x;
    if (tid < HH) cntL[tid] = 0;
    __syncthreads();

    const double TWO_PI  = 6.283185307179586476925286766559;
    const double INV_2PI = 0.15915494309189533576888376337251;

    // ---- phase 0: candidate tables (offset space), all blocks redundantly ----
    const double off0 = (double)rope_offsets[0];
    const double off1 = (double)rope_offsets[1];
    const double off2 = (double)rope_offsets[2];
    const double off3 = (double)rope_offsets[3];
    const double off4 = (double)rope_offsets[4];
    for (int i = tid; i < 2 * TT - 1; i += 320) {
        const int o = i - (TT - 1);
        const double od = (double)o;
        #pragma unroll
        for (int h = 0; h < HH; h++) {
            const double offh = (h == 0) ? off0 : (h == 1) ? off1 :
                                (h == 2) ? off2 : (h == 3) ? off3 : off4;
            const double a = od + offh;
            const double n = rint(a * INV_2PI);
            const double r = fma(-n, TWO_PI, a);
            if (fabs(r) <= THR) {
                const int p = atomicAdd(&cntL[h], 1) & (CAP - 1);
                oL[h][p] = o;
                crL[h][p] = cos(r);
            }
        }
    }
    __syncthreads();

    // ---- phase 1: one thread per (row, head) ----
    const int h = tid >> 6;          // 0..4, wave-uniform
    const int r = tid & 63;
    const int row = blockIdx.x * 64 + r;
    const int b = row >> 11;         // 32 blocks per batch
    const int t = row & 2047;
    const int* idb = ids + b * TT;

    const double C    = (double)embed_const[0];
    const double quad = 0.5 * (double)decode_eps[0];
    const double qkd  = (double)qk_scale[0];

    const int dt_i = idb[t];
    const double dtd = (double)dt_i;
    const double x0t = C - quad * dtd * dtd;
    const double K = qkd * qkd * 0.70710678118654752440 * x0t;

    const int cnt = (cntL[h] < CAP) ? cntL[h] : CAP;
    double best = -1e300;
    float bdd = 0.0f;
    for (int i = 0; i < cnt; i++) {
        const int o = oL[h][i];              // LDS broadcast (uniform addr)
        const double cr = crL[h][i];
        const int s = t + o;
        const bool valid = ((unsigned)s < (unsigned)TT);
        const double dd = (double)idb[valid ? s : 0];
        const double x0s = C - quad * dd * dd;
        double sc = K * x0s * cr;
        if (o > 0) sc -= 10000.0;            // mask (s>t <=> o>0)
        if (valid && sc > best) { best = sc; bdd = (float)dd; }
    }
    bdL[r][h] = bdd;
    __syncthreads();

    // ---- phase 2: epilogue (f32, mirrors reference element-wise math) ----
    if (tid < 64) {
        const int row_e = blockIdx.x * 64 + tid;
        const int t_e = row_e & 2047;
        const int dte = idb[t_e];

        const float Cf = embed_const[0];
        const float epsf = decode_eps[0];
        const float quadf = 0.5f * epsf;
        const float dt_f = (float)dte;
        const float x0t_f = Cf - quadf * dt_f * dt_f;

        const float a0 = bdL[tid][0], a1 = bdL[tid][1], a2 = bdL[tid][2];
        const float a3 = bdL[tid][3], a4 = bdL[tid][4];
        const float upd0 = o_w[0] * a0 + o_w[1] * a1 + o_w[2] * a2;
        const float upd1 = o_w[3] * a0 + o_w[4] * a3 + o_w[5] * a4;

        const float x0 = x0t_f + upd0;
        const float x1 = dt_f + upd1;

        const float wa = w1_abc[0], wb = w1_abc[1], wc = w1_abc[2];
        const float h0 = fmaxf(wa * x0 + (Cf - 8.0f), 0.0f);
        const float h1 = fmaxf(wa * x0 + (Cf - 9.0f), 0.0f);
        const float h2 = fmaxf(wb * x0 + wc * x1 + (2.0f * Cf - 188.0f), 0.0f);
        const float h3 = fmaxf(wb * x0 + wc * x1 + (2.0f * Cf - 189.0f), 0.0f);

        const float s1 = w2_s[0], s10 = w2_s[1];
        const float x1f = x1 + s1 * h0 - s1 * h1 - s10 * h2 + s10 * h3;

        const float y0 = x0 * (1.0f / Cf);
        const float y1 = x1f * epsf;

        #pragma unroll
        for (int v = 0; v < VV; v++) {
            const float fv = (float)v;
            const float e0 = Cf - quadf * fv * fv;
            out[(size_t)row_e * VV + v] = y0 * e0 + y1 * fv;
        }
    }
}

extern "C" void kernel_launch(void* const* d_in, const int* in_sizes, int n_in,
                              void* d_out, int out_size, void* d_ws, size_t ws_size,
                              hipStream_t stream) {
    (void)in_sizes; (void)n_in; (void)d_ws; (void)ws_size; (void)out_size;
    const int*   ids = (const int*)  d_in[0];
    const float* o_w = (const float*)d_in[1];
    const float* w1  = (const float*)d_in[2];
    const float* w2  = (const float*)d_in[3];
    const float* Cc  = (const float*)d_in[4];
    const float* ee  = (const float*)d_in[5];
    const float* qq  = (const float*)d_in[6];
    const float* ro  = (const float*)d_in[7];
    float* out = (float*)d_out;

    hipLaunchKernelGGL(transformer_fused, dim3(BB * TT / 64), dim3(320), 0,
                       stream, ids, o_w, w1, w2, Cc, ee, qq, ro, out);
}

// Round 6
// 74.825 us; speedup vs baseline: 1.0487x; 1.0487x over previous
//
#include <hip/hip_runtime.h>
#include <math.h>

#define BB 8
#define TT 2048
#define VV 10
#define HH 5
#define CAP 64            // candidate-table capacity per head (expected ~14)
#define THR 0.011         // residue window; winner provably within 7.63e-3

// Stage A: per-head candidate tables in offset space.
// score(b,h,t,s) = K * x0[b,s] * cos((s-t)+off_h) - 1e4*[s>t],
//   K = qk^2/sqrt(2) * x0[b,t]  (~4.6e10 scale), x0 in [999.9798, 1000].
// Softmax over these is one-hot => att_h = d[argmax]. The winner's residue
// r = (o+off_h) mod 2pi obeys |r| <= 7.63e-3 < THR (max circle gap 8.3e-3
// + x0 spread 0.0202 + mask 2.2e-4, normalized by x0min). So per head the
// candidate offsets o=s-t form a fixed ~14-entry subset of [-2047,2047],
// independent of t and b. Stage B scans only those.
__global__ __launch_bounds__(256) void build_tables(
    const float* __restrict__ rope_offsets,
    int* __restrict__ cnt_g, int* __restrict__ o_g, double* __restrict__ cr_g)
{
    __shared__ int cnt;
    __shared__ int o_l[CAP];
    __shared__ double cr_l[CAP];
    const int h = blockIdx.x;
    if (threadIdx.x == 0) cnt = 0;
    __syncthreads();

    const double TWO_PI  = 6.283185307179586476925286766559;
    const double INV_2PI = 0.15915494309189533576888376337251;
    const double off = (double)rope_offsets[h];

    for (int i = threadIdx.x; i < 2 * TT - 1; i += 256) {
        const int o = i - (TT - 1);
        const double a = (double)o + off;
        const double n = rint(a * INV_2PI);
        const double r = fma(-n, TWO_PI, a);
        if (fabs(r) <= THR) {
            const int p = atomicAdd(&cnt, 1) & (CAP - 1);
            o_l[p] = o;
            cr_l[p] = cos(r);
        }
    }
    __syncthreads();
    if (threadIdx.x == 0) cnt_g[h] = (cnt < CAP) ? cnt : CAP;
    if (threadIdx.x < CAP && threadIdx.x < cnt) {
        o_g[h * CAP + threadIdx.x]  = o_l[threadIdx.x];
        cr_g[h * CAP + threadIdx.x] = cr_l[threadIdx.x];
    }
}

// Stage B: one thread per (row, head). Block = 320 threads: wave w handles
// head w for 64 consecutive rows (uniform head per wave -> uniform loop
// count, no divergence). Head results exchanged via LDS; wave 0 epilogue.
__global__ __launch_bounds__(320) void attn_rows(
    const int* __restrict__ ids,
    const float* __restrict__ o_w,
    const float* __restrict__ w1_abc,
    const float* __restrict__ w2_s,
    const float* __restrict__ embed_const,
    const float* __restrict__ decode_eps,
    const float* __restrict__ qk_scale,
    const int* __restrict__ cnt_g,
    const int* __restrict__ o_g,
    const double* __restrict__ cr_g,
    float* __restrict__ out)
{
    __shared__ float bdL[64][HH];
    __shared__ int oL[HH][CAP];
    __shared__ double crL[HH][CAP];
    __shared__ int cntL[HH];

    const int tid = threadIdx.x;
    if (tid < HH) cntL[tid] = cnt_g[tid];
    for (int i = tid; i < HH * CAP; i += 320) {
        oL[i / CAP][i & (CAP - 1)]  = o_g[i];
        crL[i / CAP][i & (CAP - 1)] = cr_g[i];
    }
    __syncthreads();

    const int h = tid >> 6;          // 0..4, wave-uniform
    const int r = tid & 63;
    const int row = blockIdx.x * 64 + r;
    const int b = row >> 11;         // 32 blocks per batch
    const int t = row & 2047;
    const int* idb = ids + b * TT;

    const double C    = (double)embed_const[0];
    const double quad = 0.5 * (double)decode_eps[0];
    const double qkd  = (double)qk_scale[0];

    const int dt_i = idb[t];
    const double dtd = (double)dt_i;
    const double x0t = C - quad * dtd * dtd;
    const double K = qkd * qkd * 0.70710678118654752440 * x0t;

    const int cnt = cntL[h];
    double best = -1e300;
    float bdd = 0.0f;
    for (int i = 0; i < cnt; i++) {
        const int o = oL[h][i];              // LDS broadcast (uniform addr)
        const double cr = crL[h][i];
        const int s = t + o;
        const bool valid = ((unsigned)s < (unsigned)TT);
        const double dd = (double)idb[valid ? s : 0];
        const double x0s = C - quad * dd * dd;
        double sc = K * x0s * cr;
        if (o > 0) sc -= 10000.0;            // mask (s>t <=> o>0)
        if (valid && sc > best) { best = sc; bdd = (float)dd; }
    }
    bdL[r][h] = bdd;
    __syncthreads();

    // ---- epilogue (f32, mirrors reference element-wise math) ----
    if (tid < 64) {
        const int row_e = blockIdx.x * 64 + tid;
        const int t_e = row_e & 2047;
        const int dte = idb[t_e];

        const float Cf = embed_const[0];
        const float epsf = decode_eps[0];
        const float quadf = 0.5f * epsf;
        const float dt_f = (float)dte;
        const float x0t_f = Cf - quadf * dt_f * dt_f;

        const float a0 = bdL[tid][0], a1 = bdL[tid][1], a2 = bdL[tid][2];
        const float a3 = bdL[tid][3], a4 = bdL[tid][4];
        const float upd0 = o_w[0] * a0 + o_w[1] * a1 + o_w[2] * a2;
        const float upd1 = o_w[3] * a0 + o_w[4] * a3 + o_w[5] * a4;

        const float x0 = x0t_f + upd0;
        const float x1 = dt_f + upd1;

        const float wa = w1_abc[0], wb = w1_abc[1], wc = w1_abc[2];
        const float h0 = fmaxf(wa * x0 + (Cf - 8.0f), 0.0f);
        const float h1 = fmaxf(wa * x0 + (Cf - 9.0f), 0.0f);
        const float h2 = fmaxf(wb * x0 + wc * x1 + (2.0f * Cf - 188.0f), 0.0f);
        const float h3 = fmaxf(wb * x0 + wc * x1 + (2.0f * Cf - 189.0f), 0.0f);

        const float s1 = w2_s[0], s10 = w2_s[1];
        const float x1f = x1 + s1 * h0 - s1 * h1 - s10 * h2 + s10 * h3;

        const float y0 = x0 * (1.0f / Cf);
        const float y1 = x1f * epsf;

        #pragma unroll
        for (int v = 0; v < VV; v++) {
            const float fv = (float)v;
            const float e0 = Cf - quadf * fv * fv;
            out[(size_t)row_e * VV + v] = y0 * e0 + y1 * fv;
        }
    }
}

extern "C" void kernel_launch(void* const* d_in, const int* in_sizes, int n_in,
                              void* d_out, int out_size, void* d_ws, size_t ws_size,
                              hipStream_t stream) {
    (void)in_sizes; (void)n_in; (void)ws_size; (void)out_size;
    const int*   ids = (const int*)  d_in[0];
    const float* o_w = (const float*)d_in[1];
    const float* w1  = (const float*)d_in[2];
    const float* w2  = (const float*)d_in[3];
    const float* Cc  = (const float*)d_in[4];
    const float* ee  = (const float*)d_in[5];
    const float* qq  = (const float*)d_in[6];
    const float* ro  = (const float*)d_in[7];
    float* out = (float*)d_out;

    char* ws = (char*)d_ws;
    int*    cnt_g = (int*)ws;                      // 5 ints
    int*    o_g   = (int*)(ws + 256);              // 5*64 ints
    double* cr_g  = (double*)(ws + 2048);          // 5*64 doubles

    hipLaunchKernelGGL(build_tables, dim3(HH), dim3(256), 0, stream,
                       ro, cnt_g, o_g, cr_g);
    hipLaunchKernelGGL(attn_rows, dim3(BB * TT / 64), dim3(320), 0, stream,
                       ids, o_w, w1, w2, Cc, ee, qq, cnt_g, o_g, cr_g, out);
}